// Round 4
// baseline (921.665 us; speedup 1.0000x reference)
//
#include <hip/hip_runtime.h>
#include <hip/hip_bf16.h>

typedef __hip_bfloat16 bf16;
typedef __attribute__((ext_vector_type(8))) short short8;
typedef __attribute__((ext_vector_type(4))) float floatx4;

#define BK 64
#define LDK 72  // old reg-staged path only

// async global->LDS, 16B per lane, linear dest (wave-uniform base + lane*16)
__device__ __forceinline__ void gload_lds16(const void* g, void* l) {
    __builtin_amdgcn_global_load_lds(
        (const __attribute__((address_space(1))) void*)g,
        (__attribute__((address_space(3))) void*)l, 16, 0, 0);
}

// ---------------------------------------------------------------------------
// 256x256-tile NT GEMM, 4-phase deep-rotation pipeline (T2+T3+T4+T5).
// Regions named by their (only) read phase:
//   AX = A rows {0-63,128-191}   read p0 (af_lo, both wave groups)
//   BX = B rows {0-31,64-95,128-159,192-223}  read p0 (bf01)
//   BY = B rows {32-63,96-127,160-191,224-255} read p1 (bf23)
//   AY = A rows {64-127,192-255} read p2 (af_hi)
// K-tile kt (buffer db = kt&1):
//   p0: read af_lo+bf01; MFMA q00                    (no barrier after)
//   p1: read bf23; MFMA q01; lgkm0; BARRIER          (AX,BX,BY readers done)
//   p2: stage AX,BX(kt+2)->db; read af_hi; MFMA q11; lgkm0; BARRIER (AY done)
//   p3: stage BY,AY(kt+2)->db; MFMA q10;
//       vmcnt(8) [vmcnt(0) if kt+2>=nt] ; BARRIER    (tile kt+1 landed)
// Every staged load has >=5 phases (~3000 cyc) of flight before its deadline;
// boundary vmcnt(8) keeps tile kt+2's 8 loads in flight (T4: never drain-0).
// Requires M=N=1024 per z-slice, K mult of 64, K>=128, bf16 A/B, grid (4,4,Z).
// 8 waves (2M x 4N), per-wave C = 128x64. LDS 128 KiB.
// Source-side XOR chunk swizzle (rule #21) keeps ds_read_b128 conflict-free.
// ---------------------------------------------------------------------------
template<bool OUT_BF16>
__global__ void __launch_bounds__(512) gemm_nt_256(
    const bf16* __restrict__ A, const bf16* __restrict__ B, void* __restrict__ Cv,
    int K, int lda, int ldb, int ldc,
    long sA, long sB, long sC)
{
    __shared__ __align__(16) bf16 As[2][256 * 64];
    __shared__ __align__(16) bf16 Bs[2][256 * 64];

    int bx = blockIdx.x, by = blockIdx.y, bz = blockIdx.z;
    // XCD swizzle: each XCD owns contiguous z-slices (bijective, Z%8==0)
    if (gridDim.x == 4 && gridDim.y == 4 && (gridDim.z & 7) == 0) {
        int hw  = bx + (by << 2) + (bz << 4);
        int xcd = hw & 7;
        int idx = hw >> 3;
        int per = (int)(gridDim.z >> 3) << 4;   // blocks per XCD
        int nh  = xcd * per + idx;
        bx = nh & 3; by = (nh >> 2) & 3; bz = nh >> 4;
    }

    long aoff = (long)bz * sA + (long)by * 256 * lda;
    long boff = (long)bz * sB + (long)bx * 256 * ldb;
    long coff = (long)bz * sC;

    int tid  = threadIdx.x;
    int lane = tid & 63;
    int wave = tid >> 6;           // 0..7
    int quad = lane >> 4;
    int l16  = lane & 15;
    int swz  = l16 & 7;            // row&7 at fragment-read time
    int wm = (wave >> 2) * 128;    // 2 M-waves
    int wn = (wave & 3) * 64;      // 4 N-waves

    // staging geometry: one gload_lds per thread covers a 64-row unit
    // (512 threads x 16B = 8KB). Dest linear wave-uniform base + lane*16;
    // source carries the inverse XOR swizzle (consistent: unit bases are
    // multiples of 32, so mapped_row&7 == srow&7).
    int srow   = tid >> 3;                    // 0..63
    int schunk = (tid & 7) ^ (srow & 7);      // swizzled source chunk

    const bf16* Asrc = A + aoff;
    const bf16* Bsrc = B + boff;

    auto STA = [&](int db, int r0, int kt) {   // A rows r0..r0+63 (r0 % 64 == 0)
        long kofs = (long)kt * BK + schunk * 8;
        gload_lds16(Asrc + (long)(r0 + srow) * lda + kofs,
                    &As[db][(r0 + (wave << 3)) * 64]);
    };
    auto STB = [&](int db, int r0, int r1, int kt) { // B rows r0..+31 and r1..+31
        long kofs = (long)kt * BK + schunk * 8;
        int rr = (srow < 32) ? (r0 + srow) : (r1 + srow - 32);
        int rb = (wave < 4) ? (r0 + (wave << 3)) : (r1 + ((wave - 4) << 3));
        gload_lds16(Bsrc + (long)rr * ldb + kofs, &Bs[db][rb * 64]);
    };
    auto STAGE_AX = [&](int db, int kt){ STA(db, 0, kt);  STA(db, 128, kt); };
    auto STAGE_AY = [&](int db, int kt){ STA(db, 64, kt); STA(db, 192, kt); };
    auto STAGE_BX = [&](int db, int kt){ STB(db, 0, 64, kt);  STB(db, 128, 192, kt); };
    auto STAGE_BY = [&](int db, int kt){ STB(db, 32, 96, kt); STB(db, 160, 224, kt); };

    floatx4 acc[8][4] = {};
    const int nt = K / BK;   // REQUIRES nt >= 2

    // ---- prologue: tile0 -> buf0, tile1 -> buf1 (16 loads/thread);
    // vmcnt(8) leaves tile1's 8 in flight, requires tile0 landed.
    STAGE_AX(0, 0); STAGE_BX(0, 0); STAGE_BY(0, 0); STAGE_AY(0, 0);
    STAGE_AX(1, 1); STAGE_BX(1, 1); STAGE_BY(1, 1); STAGE_AY(1, 1);
    asm volatile("s_waitcnt vmcnt(8)" ::: "memory");
    asm volatile("s_barrier" ::: "memory");

    short8 af[4][2], bf[4][2];
    int db = 0;
    for (int kt = 0; kt < nt; kt++) {
        const bf16* as = As[db];
        const bf16* bs = Bs[db];
        bool st2 = (kt + 2 < nt);

        // ---- p0: read af_lo(AX) + bf01(BX); MFMA i0-3 x j0-1
#pragma unroll
        for (int i = 0; i < 4; i++)
#pragma unroll
            for (int ks = 0; ks < 2; ks++)
                af[i][ks] = *(const short8*)(&as[(wm + i * 16 + l16) * 64 + (((ks << 2) | quad) ^ swz) * 8]);
#pragma unroll
        for (int j = 0; j < 2; j++)
#pragma unroll
            for (int ks = 0; ks < 2; ks++)
                bf[j][ks] = *(const short8*)(&bs[(wn + j * 16 + l16) * 64 + (((ks << 2) | quad) ^ swz) * 8]);
        __builtin_amdgcn_s_setprio(1);
#pragma unroll
        for (int i = 0; i < 4; i++)
#pragma unroll
            for (int j = 0; j < 2; j++)
#pragma unroll
                for (int ks = 0; ks < 2; ks++)
                    acc[i][j] = __builtin_amdgcn_mfma_f32_16x16x32_bf16(af[i][ks], bf[j][ks], acc[i][j], 0, 0, 0);
        __builtin_amdgcn_s_setprio(0);

        // ---- p1: read bf23(BY); MFMA i0-3 x j2-3 ; end-p1 barrier
#pragma unroll
        for (int j = 2; j < 4; j++)
#pragma unroll
            for (int ks = 0; ks < 2; ks++)
                bf[j][ks] = *(const short8*)(&bs[(wn + j * 16 + l16) * 64 + (((ks << 2) | quad) ^ swz) * 8]);
        __builtin_amdgcn_s_setprio(1);
#pragma unroll
        for (int i = 0; i < 4; i++)
#pragma unroll
            for (int j = 2; j < 4; j++)
#pragma unroll
                for (int ks = 0; ks < 2; ks++)
                    acc[i][j] = __builtin_amdgcn_mfma_f32_16x16x32_bf16(af[i][ks], bf[j][ks], acc[i][j], 0, 0, 0);
        __builtin_amdgcn_s_setprio(0);
        __builtin_amdgcn_sched_barrier(0);
        asm volatile("s_waitcnt lgkmcnt(0)" ::: "memory");  // AX/BX/BY reads done
        asm volatile("s_barrier" ::: "memory");

        // ---- p2: stage AX,BX(kt+2)->db; read af_hi(AY); MFMA i4-7 x j2-3
        if (st2) { STAGE_AX(db, kt + 2); STAGE_BX(db, kt + 2); }
#pragma unroll
        for (int i = 0; i < 4; i++)
#pragma unroll
            for (int ks = 0; ks < 2; ks++)
                af[i][ks] = *(const short8*)(&as[(wm + 64 + i * 16 + l16) * 64 + (((ks << 2) | quad) ^ swz) * 8]);
        __builtin_amdgcn_sched_barrier(0);
        __builtin_amdgcn_s_setprio(1);
#pragma unroll
        for (int i = 0; i < 4; i++)
#pragma unroll
            for (int j = 2; j < 4; j++)
#pragma unroll
                for (int ks = 0; ks < 2; ks++)
                    acc[i + 4][j] = __builtin_amdgcn_mfma_f32_16x16x32_bf16(af[i][ks], bf[j][ks], acc[i + 4][j], 0, 0, 0);
        __builtin_amdgcn_s_setprio(0);
        __builtin_amdgcn_sched_barrier(0);
        asm volatile("s_waitcnt lgkmcnt(0)" ::: "memory");  // AY reads done
        asm volatile("s_barrier" ::: "memory");

        // ---- p3: stage BY,AY(kt+2)->db; MFMA i4-7 x j0-1
        if (st2) { STAGE_BY(db, kt + 2); STAGE_AY(db, kt + 2); }
        __builtin_amdgcn_sched_barrier(0);
        __builtin_amdgcn_s_setprio(1);
#pragma unroll
        for (int i = 0; i < 4; i++)
#pragma unroll
            for (int j = 0; j < 2; j++)
#pragma unroll
                for (int ks = 0; ks < 2; ks++)
                    acc[i + 4][j] = __builtin_amdgcn_mfma_f32_16x16x32_bf16(af[i][ks], bf[j][ks], acc[i + 4][j], 0, 0, 0);
        __builtin_amdgcn_s_setprio(0);
        __builtin_amdgcn_sched_barrier(0);

        // ---- boundary: tile kt+1 (issued a full K-tile ago) must be landed;
        // keep tile kt+2's 8 loads in flight (never drain to 0 mid-loop).
        if (kt + 1 < nt) {
            if (st2) asm volatile("s_waitcnt vmcnt(8)" ::: "memory");
            else     asm volatile("s_waitcnt vmcnt(0)" ::: "memory");
            asm volatile("s_barrier" ::: "memory");
        }
        db ^= 1;
    }

    // epilogue: C/D layout row = quad*4+reg, col = lane&15
#pragma unroll
    for (int i = 0; i < 8; i++) {
        int row = by * 256 + wm + i * 16 + quad * 4;
#pragma unroll
        for (int j = 0; j < 4; j++) {
            int col = bx * 256 + wn + j * 16 + l16;
#pragma unroll
            for (int v = 0; v < 4; v++) {
                float val = acc[i][j][v];
                if (OUT_BF16)
                    ((bf16*)Cv)[coff + (long)(row + v) * ldc + col] = __float2bfloat16(val);
                else
                    ((float*)Cv)[coff + (long)(row + v) * ldc + col] = val;
            }
        }
    }
}

// ---------------------------------------------------------------------------
// OLD reg-staged NT GEMM: kept only for the small Q/K projections
// (N=64 needs bounds guards; A is f32 converted at LDS-store time).
// ---------------------------------------------------------------------------
template<bool OUT_BF16, bool A_F32, bool B_F32>
__global__ void __launch_bounds__(256) gemm_nt(
    const void* __restrict__ Av, const void* __restrict__ Bv, void* __restrict__ Cv,
    int M, int N, int K, int lda, int ldb, int ldc,
    long sA, long sB, long sC)
{
    __shared__ __align__(16) bf16 As[128 * LDK];
    __shared__ __align__(16) bf16 Bs[128 * LDK];

    int bx = blockIdx.x, by = blockIdx.y, bz = blockIdx.z;

    long aoff = (long)bz * sA;
    long boff = (long)bz * sB;
    long coff = (long)bz * sC;

    int m0 = by * 128;
    int n0 = bx * 128;
    int tid  = threadIdx.x;
    int lane = tid & 63;
    int wave = tid >> 6;
    int quad = lane >> 4;
    int l16  = lane & 15;
    int wm = (wave >> 1) * 64;
    int wn = (wave & 1) * 64;

    int sr = tid >> 3;
    int sc = (tid & 7) * 8;

    floatx4 acc[4][4] = {};

    uint4  pa[4], pb[4];
    float4 pa0[4], pa1[4], pb0[4], pb1[4];

    const int nt = K / BK;

#pragma unroll
    for (int s = 0; s < 4; s++) {
        int r = sr + 32 * s;
        int gm = m0 + r;
        if (A_F32) {
            const float* p = (const float*)Av + aoff + (long)gm * lda + sc;
            if (gm < M) { pa0[s] = *(const float4*)p; pa1[s] = *(const float4*)(p + 4); }
            else { pa0[s] = {0,0,0,0}; pa1[s] = {0,0,0,0}; }
        } else {
            pa[s] = (gm < M) ? *(const uint4*)((const bf16*)Av + aoff + (long)gm * lda + sc)
                             : (uint4){0,0,0,0};
        }
        int gn = n0 + r;
        if (B_F32) {
            const float* p = (const float*)Bv + boff + (long)gn * ldb + sc;
            if (gn < N) { pb0[s] = *(const float4*)p; pb1[s] = *(const float4*)(p + 4); }
            else { pb0[s] = {0,0,0,0}; pb1[s] = {0,0,0,0}; }
        } else {
            pb[s] = (gn < N) ? *(const uint4*)((const bf16*)Bv + boff + (long)gn * ldb + sc)
                             : (uint4){0,0,0,0};
        }
    }

    for (int kt = 0; kt < nt; kt++) {
        __syncthreads();
#pragma unroll
        for (int s = 0; s < 4; s++) {
            int r = sr + 32 * s;
            if (A_F32) {
                bf16 t[8];
                t[0]=__float2bfloat16(pa0[s].x); t[1]=__float2bfloat16(pa0[s].y);
                t[2]=__float2bfloat16(pa0[s].z); t[3]=__float2bfloat16(pa0[s].w);
                t[4]=__float2bfloat16(pa1[s].x); t[5]=__float2bfloat16(pa1[s].y);
                t[6]=__float2bfloat16(pa1[s].z); t[7]=__float2bfloat16(pa1[s].w);
                *(uint4*)(&As[r * LDK + sc]) = *(const uint4*)t;
            } else {
                *(uint4*)(&As[r * LDK + sc]) = pa[s];
            }
            if (B_F32) {
                bf16 t[8];
                t[0]=__float2bfloat16(pb0[s].x); t[1]=__float2bfloat16(pb0[s].y);
                t[2]=__float2bfloat16(pb0[s].z); t[3]=__float2bfloat16(pb0[s].w);
                t[4]=__float2bfloat16(pb1[s].x); t[5]=__float2bfloat16(pb1[s].y);
                t[6]=__float2bfloat16(pb1[s].z); t[7]=__float2bfloat16(pb1[s].w);
                *(uint4*)(&Bs[r * LDK + sc]) = *(const uint4*)t;
            } else {
                *(uint4*)(&Bs[r * LDK + sc]) = pb[s];
            }
        }
        __syncthreads();

        if (kt + 1 < nt) {
            int k0 = (kt + 1) * BK;
#pragma unroll
            for (int s = 0; s < 4; s++) {
                int r = sr + 32 * s;
                int gm = m0 + r;
                if (A_F32) {
                    const float* p = (const float*)Av + aoff + (long)gm * lda + k0 + sc;
                    if (gm < M) { pa0[s] = *(const float4*)p; pa1[s] = *(const float4*)(p + 4); }
                    else { pa0[s] = {0,0,0,0}; pa1[s] = {0,0,0,0}; }
                } else {
                    pa[s] = (gm < M) ? *(const uint4*)((const bf16*)Av + aoff + (long)gm * lda + k0 + sc)
                                     : (uint4){0,0,0,0};
                }
                int gn = n0 + r;
                if (B_F32) {
                    const float* p = (const float*)Bv + boff + (long)gn * ldb + k0 + sc;
                    if (gn < N) { pb0[s] = *(const float4*)p; pb1[s] = *(const float4*)(p + 4); }
                    else { pb0[s] = {0,0,0,0}; pb1[s] = {0,0,0,0}; }
                } else {
                    pb[s] = (gn < N) ? *(const uint4*)((const bf16*)Bv + boff + (long)gn * ldb + k0 + sc)
                                     : (uint4){0,0,0,0};
                }
            }
        }

#pragma unroll
        for (int ks = 0; ks < 2; ks++) {
            short8 af[4], bfr[4];
#pragma unroll
            for (int i = 0; i < 4; i++)
                af[i] = *(const short8*)(&As[(wm + i * 16 + l16) * LDK + ks * 32 + quad * 8]);
#pragma unroll
            for (int j = 0; j < 4; j++)
                bfr[j] = *(const short8*)(&Bs[(wn + j * 16 + l16) * LDK + ks * 32 + quad * 8]);
#pragma unroll
            for (int i = 0; i < 4; i++)
#pragma unroll
                for (int j = 0; j < 4; j++)
                    acc[i][j] = __builtin_amdgcn_mfma_f32_16x16x32_bf16(af[i], bfr[j], acc[i][j], 0, 0, 0);
        }
    }

#pragma unroll
    for (int i = 0; i < 4; i++) {
        int row = m0 + wm + i * 16 + quad * 4;
#pragma unroll
        for (int j = 0; j < 4; j++) {
            int col = n0 + wn + j * 16 + l16;
            if (col >= N) continue;
#pragma unroll
            for (int v = 0; v < 4; v++) {
                int r = row + v;
                if (r < M) {
                    float val = acc[i][j][v];
                    if (OUT_BF16)
                        ((bf16*)Cv)[coff + (long)r * ldc + col] = __float2bfloat16(val);
                    else
                        ((float*)Cv)[coff + (long)r * ldc + col] = val;
                }
            }
        }
    }
}

// ---------------------------------------------------------------------------
// Fused QK^T + online softmax, ONE batch (round-4 PROVEN, unchanged).
// ---------------------------------------------------------------------------
__global__ void __launch_bounds__(256) attn_softmax(
    const bf16* __restrict__ Q, const bf16* __restrict__ Kb, bf16* __restrict__ Wts)
{
    __shared__ __align__(16) bf16 Ks[64 * 72];

    int h = blockIdx.y;
    const bf16* Qbh = Q  + (long)h * 262144;
    const bf16* Kbh = Kb + (long)h * 262144;
    bf16* W = Wts + (long)h * 1048576;

    int tid  = threadIdx.x;
    int lane = tid & 63;
    int wave = tid >> 6;
    int quad = lane >> 4;
    int l16  = lane & 15;
    int q0 = blockIdx.x * 64 + wave * 16;

    short8 a0 = *(const short8*)(Qbh + (long)(q0 + l16) * 64 + quad * 8);
    short8 a1 = *(const short8*)(Qbh + (long)(q0 + l16) * 64 + 32 + quad * 8);

    int sr = tid >> 3;
    int sc = (tid & 7) * 8;

    const float scale = 0.125f;
    float m_v[4] = {-1e30f, -1e30f, -1e30f, -1e30f};
    float l_v[4] = {0.f, 0.f, 0.f, 0.f};

    for (int t = 0; t < 16; t++) {
        __syncthreads();
        const bf16* src = Kbh + (long)(t * 64 + sr) * 64 + sc;
        *(uint4*)(&Ks[sr * 72 + sc])        = *(const uint4*)src;
        *(uint4*)(&Ks[(sr + 32) * 72 + sc]) = *(const uint4*)(src + 32 * 64);
        __syncthreads();
#pragma unroll
        for (int j = 0; j < 4; j++) {
            short8 b0 = *(const short8*)(&Ks[(j * 16 + l16) * 72 + quad * 8]);
            short8 b1 = *(const short8*)(&Ks[(j * 16 + l16) * 72 + 32 + quad * 8]);
            floatx4 acc = {0.f, 0.f, 0.f, 0.f};
            acc = __builtin_amdgcn_mfma_f32_16x16x32_bf16(a0, b0, acc, 0, 0, 0);
            acc = __builtin_amdgcn_mfma_f32_16x16x32_bf16(a1, b1, acc, 0, 0, 0);
#pragma unroll
            for (int v = 0; v < 4; v++) {
                float s  = acc[v] * scale;
                float nm = fmaxf(m_v[v], s);
                l_v[v] = l_v[v] * __expf(m_v[v] - nm) + __expf(s - nm);
                m_v[v] = nm;
            }
        }
    }

#pragma unroll
    for (int d = 1; d < 16; d <<= 1) {
#pragma unroll
        for (int v = 0; v < 4; v++) {
            float om = __shfl_xor(m_v[v], d);
            float ol = __shfl_xor(l_v[v], d);
            float nm = fmaxf(m_v[v], om);
            l_v[v] = l_v[v] * __expf(m_v[v] - nm) + ol * __expf(om - nm);
            m_v[v] = nm;
        }
    }
    float linv[4];
#pragma unroll
    for (int v = 0; v < 4; v++) linv[v] = 1.0f / l_v[v];

    for (int t = 0; t < 16; t++) {
        __syncthreads();
        const bf16* src = Kbh + (long)(t * 64 + sr) * 64 + sc;
        *(uint4*)(&Ks[sr * 72 + sc])        = *(const uint4*)src;
        *(uint4*)(&Ks[(sr + 32) * 72 + sc]) = *(const uint4*)(src + 32 * 64);
        __syncthreads();
#pragma unroll
        for (int j = 0; j < 4; j++) {
            short8 b0 = *(const short8*)(&Ks[(j * 16 + l16) * 72 + quad * 8]);
            short8 b1 = *(const short8*)(&Ks[(j * 16 + l16) * 72 + 32 + quad * 8]);
            floatx4 acc = {0.f, 0.f, 0.f, 0.f};
            acc = __builtin_amdgcn_mfma_f32_16x16x32_bf16(a0, b0, acc, 0, 0, 0);
            acc = __builtin_amdgcn_mfma_f32_16x16x32_bf16(a1, b1, acc, 0, 0, 0);
#pragma unroll
            for (int v = 0; v < 4; v++) {
                float w = __expf(acc[v] * scale - m_v[v]) * linv[v];
                W[(long)(q0 + quad * 4 + v) * 1024 + t * 64 + j * 16 + l16] = __float2bfloat16(w);
            }
        }
    }
}

// ---------------------------------------------------------------------------
__global__ void __launch_bounds__(256) cast_bf16_k(
    const float* __restrict__ in, bf16* __restrict__ out, int n4)
{
    int i = blockIdx.x * 256 + threadIdx.x;
    if (i >= n4) return;
    float4 v = ((const float4*)in)[i];
    bf16 t[4] = {__float2bfloat16(v.x), __float2bfloat16(v.y),
                 __float2bfloat16(v.z), __float2bfloat16(v.w)};
    ((uint2*)out)[i] = *(const uint2*)t;
}

__global__ void __launch_bounds__(256) transpose_cast(
    const float* __restrict__ in, bf16* __restrict__ out, int R, int C)
{
    __shared__ float t[32][33];
    int h = blockIdx.z;
    const float* inh = in + (long)h * R * C;
    bf16* outh = out + (long)h * R * C;
    int c0 = blockIdx.x * 32, r0 = blockIdx.y * 32;
    int tx = threadIdx.x, ty = threadIdx.y;
#pragma unroll
    for (int i = 0; i < 32; i += 8)
        t[ty + i][tx] = inh[(long)(r0 + ty + i) * C + c0 + tx];
    __syncthreads();
#pragma unroll
    for (int i = 0; i < 32; i += 8)
        outh[(long)(c0 + ty + i) * R + r0 + tx] = __float2bfloat16(t[tx][ty + i]);
}

// sum 16 fp32 partials of 1M elems each -> out (float4 per thread)
__global__ void __launch_bounds__(256) reduce16_k(
    const float* __restrict__ part, float* __restrict__ out)
{
    int i = blockIdx.x * 256 + threadIdx.x;
    float4 s = ((const float4*)part)[i];
#pragma unroll
    for (int c = 1; c < 16; c++) {
        float4 p = ((const float4*)part)[c * 262144 + i];
        s.x += p.x; s.y += p.y; s.z += p.z; s.w += p.w;
    }
    ((float4*)out)[i] = s;
}

// ---------------------------------------------------------------------------
// Workspace (MB, max 180 — proven):
//   wqt 0..2 | wkt 2..4 | wvt 4..36 | wob 36..68 | qb 68..76 | kb 76..84 |
//   vt_b 84..116 | wts_b 116..148 | att_b 148..180
//   out_part overlays 84..148 (vt_b/wts_b dead when final GEMM runs).
//   value_bf overlays 148..150 (att_b region; dead until PV GEMM, which runs
//   after vt GEMM has consumed value_bf — stream-ordered, safe).
// ---------------------------------------------------------------------------
extern "C" void kernel_launch(void* const* d_in, const int* in_sizes, int n_in,
                              void* d_out, int out_size, void* d_ws, size_t ws_size,
                              hipStream_t stream) {
    const float* query = (const float*)d_in[0];
    const float* key   = (const float*)d_in[1];
    const float* value = (const float*)d_in[2];
    const float* w_q   = (const float*)d_in[3];
    const float* w_k   = (const float*)d_in[4];
    const float* w_v   = (const float*)d_in[5];
    const float* w_o   = (const float*)d_in[6];
    float* out = (float*)d_out;

    char* ws = (char*)d_ws;
    const size_t MB = (size_t)1 << 20;
    bf16* wqt      = (bf16*)(ws + 0 * MB);
    bf16* wkt      = (bf16*)(ws + 2 * MB);
    bf16* wvt      = (bf16*)(ws + 4 * MB);
    bf16* wob      = (bf16*)(ws + 36 * MB);
    bf16* qb       = (bf16*)(ws + 68 * MB);
    bf16* kb       = (bf16*)(ws + 76 * MB);
    bf16* vt_b     = (bf16*)(ws + 84 * MB);
    bf16* wts_b    = (bf16*)(ws + 116 * MB);
    bf16* att_b    = (bf16*)(ws + 148 * MB);
    bf16* value_bf = (bf16*)(ws + 148 * MB);    // 2 MB overlay on att_b head
    float* out_part = (float*)(ws + 84 * MB);   // 64 MB overlay

    // weight prep
    transpose_cast<<<dim3(2, 32, 16),  dim3(32, 8), 0, stream>>>(w_q, wqt, 1024, 64);
    transpose_cast<<<dim3(2, 32, 16),  dim3(32, 8), 0, stream>>>(w_k, wkt, 1024, 64);
    transpose_cast<<<dim3(32, 32, 16), dim3(32, 8), 0, stream>>>(w_v, wvt, 1024, 1024);
    cast_bf16_k<<<16384, 256, 0, stream>>>(w_o, wob, 1024 * 16384 / 4);

    // Q/K projections (small, N=64 — old guarded reg-staged path)
    gemm_nt<true, true, false><<<dim3(1, 32, 16), 256, 0, stream>>>(
        query, wqt, qb, 4096, 64, 1024, 1024, 1024, 64, 0L, 65536L, 262144L);
    gemm_nt<true, true, false><<<dim3(1, 32, 16), 256, 0, stream>>>(
        key, wkt, kb, 4096, 64, 1024, 1024, 1024, 64, 0L, 65536L, 262144L);

    for (int b = 0; b < 4; b++) {
        // cast this batch's value to bf16 (enables global_load_lds path)
        cast_bf16_k<<<1024, 256, 0, stream>>>(value + (long)b * 1048576, value_bf, 262144);

        // V^T proj: vt_b[h][v][m] = wvt[h][v][d] . value_b[m][d]^T
        gemm_nt_256<true><<<dim3(4, 4, 16), 512, 0, stream>>>(
            wvt, value_bf, vt_b,
            1024, 1024, 1024, 1024, 1048576L, 0L, 1048576L);

        // QK^T + softmax -> wts_b[h][q][m]
        attn_softmax<<<dim3(16, 16), 256, 0, stream>>>(
            qb + (long)b * 65536, kb + (long)b * 65536, wts_b);

        // PV^T: att_b[v][h*1024+q] = vt_b[h][v][m] . wts_b[h][q][m]^T
        gemm_nt_256<true><<<dim3(4, 4, 16), 512, 0, stream>>>(
            vt_b, wts_b, att_b,
            1024, 1024, 1024, 16384, 1048576L, 1048576L, 1024L);

        // final split-K over heads: out_part[h][d][v] = wo[d][h*1024+q] . att_b[v][h*1024+q]^T
        gemm_nt_256<false><<<dim3(4, 4, 16), 512, 0, stream>>>(
            wob, att_b, out_part,
            1024, 16384, 16384, 1024, 1024L, 1024L, 1048576L);

        // reduce 16 partials -> out[b]
        reduce16_k<<<1024, 256, 0, stream>>>(out_part, out + (long)b * 1048576);
    }

    (void)in_sizes; (void)n_in; (void)out_size; (void)ws_size;
}

// Round 5
// 882.059 us; speedup vs baseline: 1.0449x; 1.0449x over previous
//
#include <hip/hip_runtime.h>
#include <hip/hip_bf16.h>

typedef __hip_bfloat16 bf16;
typedef __attribute__((ext_vector_type(8))) short short8;
typedef __attribute__((ext_vector_type(4))) float floatx4;

#define BK 64
#define LDK 72  // old reg-staged path only

// async global->LDS, 16B per lane, linear dest (wave-uniform base + lane*16)
__device__ __forceinline__ void gload_lds16(const void* g, void* l) {
    __builtin_amdgcn_global_load_lds(
        (const __attribute__((address_space(1))) void*)g,
        (__attribute__((address_space(3))) void*)l, 16, 0, 0);
}

// ---------------------------------------------------------------------------
// 256x256-tile NT GEMM — m201-style 4-phase/K-tile schedule with per-phase
// barrier pairs, 1 half-tile stage per phase (ring, issued 7 phases ahead),
// counted vmcnt(6) once per K-tile (T2+T3+T4+T5).
// Regions (read-phase-aligned row sets, addressing proven in prior round):
//   AX = A rows {0-63,128-191}    read P0 (af_lo)
//   BX = B rows {0-31,64-95,128-159,192-223}   read P0 (bf01)
//   BY = B rows {32-63,96-127,160-191,224-255} read P1 (bf23)
//   AY = A rows {64-127,192-255}  read P2 (af_hi)
// K-tile kt, buf d = kt&1. Phase = {ds_reads ; stage 1 unit ; BAR ; lgkm0 ;
//   setprio1 ; 16 MFMA ; setprio0 ; BAR}:
//   P0: read af_lo+bf01 (12 b128); stage AY(kt+1)->d^1 ; MFMA q00 (i0-3,j0-1)
//   P1: read bf23 (4);             stage AX(kt+2)->d   ; MFMA q01 (i0-3,j2-3)
//   P2: read af_hi (8);            stage BX(kt+2)->d   ; MFMA q11 (i4-7,j2-3)
//   P3:                            stage BY(kt+2)->d   ; vmcnt(6) ; MFMA q10
// Ledger: each region's last reader is >=1 barrier-pair before its overwrite
// (AX rd@P0/st@P1; BX rd@P0/st@P2; BY rd@P1/st@P3; AY rd@P2/st@P0-next).
// Boundary vmcnt(6) = 3 units in flight -> AY(kt+1) and older landed; all of
// tile kt+1 ready entering its phases. vmcnt(0) entering the last K-tile.
// Requires M=N=1024 per z-slice, K mult of 64, K>=128, bf16 A/B, grid (4,4,Z).
// 8 waves (2M x 4N), per-wave C = 128x64. LDS 128 KiB.
// Source-side XOR chunk swizzle (rule #21) keeps ds_read_b128 conflict-free.
// ---------------------------------------------------------------------------
template<bool OUT_BF16>
__global__ void __launch_bounds__(512) gemm_nt_256(
    const bf16* __restrict__ A, const bf16* __restrict__ B, void* __restrict__ Cv,
    int K, int lda, int ldb, int ldc,
    long sA, long sB, long sC)
{
    __shared__ __align__(16) bf16 As[2][256 * 64];
    __shared__ __align__(16) bf16 Bs[2][256 * 64];

    int bx = blockIdx.x, by = blockIdx.y, bz = blockIdx.z;
    // XCD swizzle: each XCD owns contiguous z-slices (bijective, Z%8==0)
    if (gridDim.x == 4 && gridDim.y == 4 && (gridDim.z & 7) == 0) {
        int hw  = bx + (by << 2) + (bz << 4);
        int xcd = hw & 7;
        int idx = hw >> 3;
        int per = (int)(gridDim.z >> 3) << 4;   // blocks per XCD
        int nh  = xcd * per + idx;
        bx = nh & 3; by = (nh >> 2) & 3; bz = nh >> 4;
    }

    long aoff = (long)bz * sA + (long)by * 256 * lda;
    long boff = (long)bz * sB + (long)bx * 256 * ldb;
    long coff = (long)bz * sC;

    int tid  = threadIdx.x;
    int lane = tid & 63;
    int wave = tid >> 6;           // 0..7
    int quad = lane >> 4;
    int l16  = lane & 15;
    int swz  = l16 & 7;            // row&7 at fragment-read time
    int wm = (wave >> 2) * 128;    // 2 M-waves
    int wn = (wave & 3) * 64;      // 4 N-waves

    // staging geometry: one gload_lds per thread covers a 64-row unit
    // (512 threads x 16B = 8KB). Dest linear wave-uniform base + lane*16;
    // source carries the inverse XOR swizzle.
    int srow   = tid >> 3;                    // 0..63
    int schunk = (tid & 7) ^ (srow & 7);      // swizzled source chunk

    const bf16* Asrc = A + aoff;
    const bf16* Bsrc = B + boff;

    auto STA = [&](int db_, int r0, int kt) {  // A rows r0..r0+63 (r0 % 64 == 0)
        long kofs = (long)kt * BK + schunk * 8;
        gload_lds16(Asrc + (long)(r0 + srow) * lda + kofs,
                    &As[db_][(r0 + (wave << 3)) * 64]);
    };
    auto STB = [&](int db_, int r0, int r1, int kt) { // B rows r0..+31 and r1..+31
        long kofs = (long)kt * BK + schunk * 8;
        int rr = (srow < 32) ? (r0 + srow) : (r1 + srow - 32);
        int rb = (wave < 4) ? (r0 + (wave << 3)) : (r1 + ((wave - 4) << 3));
        gload_lds16(Bsrc + (long)rr * ldb + kofs, &Bs[db_][rb * 64]);
    };
    auto STAGE_AX = [&](int db_, int kt){ STA(db_, 0, kt);  STA(db_, 128, kt); };
    auto STAGE_AY = [&](int db_, int kt){ STA(db_, 64, kt); STA(db_, 192, kt); };
    auto STAGE_BX = [&](int db_, int kt){ STB(db_, 0, 64, kt);  STB(db_, 128, 192, kt); };
    auto STAGE_BY = [&](int db_, int kt){ STB(db_, 32, 96, kt); STB(db_, 160, 224, kt); };

    floatx4 acc[8][4] = {};
    const int nt = K / BK;   // REQUIRES nt >= 2

    // ---- prologue: 7 units in ring order (tile0 all 4 + tile1 AX,BX,BY);
    // vmcnt(6) -> tile0 fully landed, tile1's 3 units (6 loads) in flight.
    STAGE_AX(0, 0); STAGE_BX(0, 0); STAGE_BY(0, 0); STAGE_AY(0, 0);
    STAGE_AX(1, 1); STAGE_BX(1, 1); STAGE_BY(1, 1);
    asm volatile("s_waitcnt vmcnt(6)" ::: "memory");
    __builtin_amdgcn_sched_barrier(0);
    asm volatile("s_barrier" ::: "memory");

    short8 af[4][2], bf[4][2];
    int db = 0;
    for (int kt = 0; kt < nt; kt++) {
        const bf16* as = As[db];
        const bf16* bs = Bs[db];
        bool st1 = (kt + 1 < nt);
        bool st2 = (kt + 2 < nt);

        // ================= P0: read af_lo + bf01 ; stage AY(kt+1)->d^1
#pragma unroll
        for (int i = 0; i < 4; i++)
#pragma unroll
            for (int ks = 0; ks < 2; ks++)
                af[i][ks] = *(const short8*)(&as[(wm + i * 16 + l16) * 64 + (((ks << 2) | quad) ^ swz) * 8]);
#pragma unroll
        for (int j = 0; j < 2; j++)
#pragma unroll
            for (int ks = 0; ks < 2; ks++)
                bf[j][ks] = *(const short8*)(&bs[(wn + j * 16 + l16) * 64 + (((ks << 2) | quad) ^ swz) * 8]);
        if (st1) STAGE_AY(db ^ 1, kt + 1);
        __builtin_amdgcn_sched_barrier(0);
        asm volatile("s_barrier" ::: "memory");
        asm volatile("s_waitcnt lgkmcnt(0)" ::: "memory");
        __builtin_amdgcn_sched_barrier(0);
        __builtin_amdgcn_s_setprio(1);
#pragma unroll
        for (int i = 0; i < 4; i++)
#pragma unroll
            for (int j = 0; j < 2; j++)
#pragma unroll
                for (int ks = 0; ks < 2; ks++)
                    acc[i][j] = __builtin_amdgcn_mfma_f32_16x16x32_bf16(af[i][ks], bf[j][ks], acc[i][j], 0, 0, 0);
        __builtin_amdgcn_s_setprio(0);
        __builtin_amdgcn_sched_barrier(0);
        asm volatile("s_barrier" ::: "memory");

        // ================= P1: read bf23 ; stage AX(kt+2)->d
#pragma unroll
        for (int j = 2; j < 4; j++)
#pragma unroll
            for (int ks = 0; ks < 2; ks++)
                bf[j][ks] = *(const short8*)(&bs[(wn + j * 16 + l16) * 64 + (((ks << 2) | quad) ^ swz) * 8]);
        if (st2) STAGE_AX(db, kt + 2);
        __builtin_amdgcn_sched_barrier(0);
        asm volatile("s_barrier" ::: "memory");
        asm volatile("s_waitcnt lgkmcnt(0)" ::: "memory");
        __builtin_amdgcn_sched_barrier(0);
        __builtin_amdgcn_s_setprio(1);
#pragma unroll
        for (int i = 0; i < 4; i++)
#pragma unroll
            for (int j = 2; j < 4; j++)
#pragma unroll
                for (int ks = 0; ks < 2; ks++)
                    acc[i][j] = __builtin_amdgcn_mfma_f32_16x16x32_bf16(af[i][ks], bf[j][ks], acc[i][j], 0, 0, 0);
        __builtin_amdgcn_s_setprio(0);
        __builtin_amdgcn_sched_barrier(0);
        asm volatile("s_barrier" ::: "memory");

        // ================= P2: read af_hi ; stage BX(kt+2)->d
#pragma unroll
        for (int i = 0; i < 4; i++)
#pragma unroll
            for (int ks = 0; ks < 2; ks++)
                af[i][ks] = *(const short8*)(&as[(wm + 64 + i * 16 + l16) * 64 + (((ks << 2) | quad) ^ swz) * 8]);
        if (st2) STAGE_BX(db, kt + 2);
        __builtin_amdgcn_sched_barrier(0);
        asm volatile("s_barrier" ::: "memory");
        asm volatile("s_waitcnt lgkmcnt(0)" ::: "memory");
        __builtin_amdgcn_sched_barrier(0);
        __builtin_amdgcn_s_setprio(1);
#pragma unroll
        for (int i = 0; i < 4; i++)
#pragma unroll
            for (int j = 2; j < 4; j++)
#pragma unroll
                for (int ks = 0; ks < 2; ks++)
                    acc[i + 4][j] = __builtin_amdgcn_mfma_f32_16x16x32_bf16(af[i][ks], bf[j][ks], acc[i + 4][j], 0, 0, 0);
        __builtin_amdgcn_s_setprio(0);
        __builtin_amdgcn_sched_barrier(0);
        asm volatile("s_barrier" ::: "memory");

        // ================= P3: stage BY(kt+2)->d ; vmcnt(6|0) ; MFMA q10
        if (st2) STAGE_BY(db, kt + 2);
        if (st2) asm volatile("s_waitcnt vmcnt(6)" ::: "memory");
        else     asm volatile("s_waitcnt vmcnt(0)" ::: "memory");
        __builtin_amdgcn_sched_barrier(0);
        asm volatile("s_barrier" ::: "memory");
        __builtin_amdgcn_s_setprio(1);
#pragma unroll
        for (int i = 0; i < 4; i++)
#pragma unroll
            for (int j = 0; j < 2; j++)
#pragma unroll
                for (int ks = 0; ks < 2; ks++)
                    acc[i + 4][j] = __builtin_amdgcn_mfma_f32_16x16x32_bf16(af[i][ks], bf[j][ks], acc[i + 4][j], 0, 0, 0);
        __builtin_amdgcn_s_setprio(0);
        __builtin_amdgcn_sched_barrier(0);
        asm volatile("s_barrier" ::: "memory");

        db ^= 1;
    }

    // epilogue: C/D layout row = quad*4+reg, col = lane&15
#pragma unroll
    for (int i = 0; i < 8; i++) {
        int row = by * 256 + wm + i * 16 + quad * 4;
#pragma unroll
        for (int j = 0; j < 4; j++) {
            int col = bx * 256 + wn + j * 16 + l16;
#pragma unroll
            for (int v = 0; v < 4; v++) {
                float val = acc[i][j][v];
                if (OUT_BF16)
                    ((bf16*)Cv)[coff + (long)(row + v) * ldc + col] = __float2bfloat16(val);
                else
                    ((float*)Cv)[coff + (long)(row + v) * ldc + col] = val;
            }
        }
    }
}

// ---------------------------------------------------------------------------
// OLD reg-staged NT GEMM: kept only for the small Q/K projections
// (N=64 needs bounds guards; A is f32 converted at LDS-store time).
// ---------------------------------------------------------------------------
template<bool OUT_BF16, bool A_F32, bool B_F32>
__global__ void __launch_bounds__(256) gemm_nt(
    const void* __restrict__ Av, const void* __restrict__ Bv, void* __restrict__ Cv,
    int M, int N, int K, int lda, int ldb, int ldc,
    long sA, long sB, long sC)
{
    __shared__ __align__(16) bf16 As[128 * LDK];
    __shared__ __align__(16) bf16 Bs[128 * LDK];

    int bx = blockIdx.x, by = blockIdx.y, bz = blockIdx.z;

    long aoff = (long)bz * sA;
    long boff = (long)bz * sB;
    long coff = (long)bz * sC;

    int m0 = by * 128;
    int n0 = bx * 128;
    int tid  = threadIdx.x;
    int lane = tid & 63;
    int wave = tid >> 6;
    int quad = lane >> 4;
    int l16  = lane & 15;
    int wm = (wave >> 1) * 64;
    int wn = (wave & 1) * 64;

    int sr = tid >> 3;
    int sc = (tid & 7) * 8;

    floatx4 acc[4][4] = {};

    uint4  pa[4], pb[4];
    float4 pa0[4], pa1[4], pb0[4], pb1[4];

    const int nt = K / BK;

#pragma unroll
    for (int s = 0; s < 4; s++) {
        int r = sr + 32 * s;
        int gm = m0 + r;
        if (A_F32) {
            const float* p = (const float*)Av + aoff + (long)gm * lda + sc;
            if (gm < M) { pa0[s] = *(const float4*)p; pa1[s] = *(const float4*)(p + 4); }
            else { pa0[s] = {0,0,0,0}; pa1[s] = {0,0,0,0}; }
        } else {
            pa[s] = (gm < M) ? *(const uint4*)((const bf16*)Av + aoff + (long)gm * lda + sc)
                             : (uint4){0,0,0,0};
        }
        int gn = n0 + r;
        if (B_F32) {
            const float* p = (const float*)Bv + boff + (long)gn * ldb + sc;
            if (gn < N) { pb0[s] = *(const float4*)p; pb1[s] = *(const float4*)(p + 4); }
            else { pb0[s] = {0,0,0,0}; pb1[s] = {0,0,0,0}; }
        } else {
            pb[s] = (gn < N) ? *(const uint4*)((const bf16*)Bv + boff + (long)gn * ldb + sc)
                             : (uint4){0,0,0,0};
        }
    }

    for (int kt = 0; kt < nt; kt++) {
        __syncthreads();
#pragma unroll
        for (int s = 0; s < 4; s++) {
            int r = sr + 32 * s;
            if (A_F32) {
                bf16 t[8];
                t[0]=__float2bfloat16(pa0[s].x); t[1]=__float2bfloat16(pa0[s].y);
                t[2]=__float2bfloat16(pa0[s].z); t[3]=__float2bfloat16(pa0[s].w);
                t[4]=__float2bfloat16(pa1[s].x); t[5]=__float2bfloat16(pa1[s].y);
                t[6]=__float2bfloat16(pa1[s].z); t[7]=__float2bfloat16(pa1[s].w);
                *(uint4*)(&As[r * LDK + sc]) = *(const uint4*)t;
            } else {
                *(uint4*)(&As[r * LDK + sc]) = pa[s];
            }
            if (B_F32) {
                bf16 t[8];
                t[0]=__float2bfloat16(pb0[s].x); t[1]=__float2bfloat16(pb0[s].y);
                t[2]=__float2bfloat16(pb0[s].z); t[3]=__float2bfloat16(pb0[s].w);
                t[4]=__float2bfloat16(pb1[s].x); t[5]=__float2bfloat16(pb1[s].y);
                t[6]=__float2bfloat16(pb1[s].z); t[7]=__float2bfloat16(pb1[s].w);
                *(uint4*)(&Bs[r * LDK + sc]) = *(const uint4*)t;
            } else {
                *(uint4*)(&Bs[r * LDK + sc]) = pb[s];
            }
        }
        __syncthreads();

        if (kt + 1 < nt) {
            int k0 = (kt + 1) * BK;
#pragma unroll
            for (int s = 0; s < 4; s++) {
                int r = sr + 32 * s;
                int gm = m0 + r;
                if (A_F32) {
                    const float* p = (const float*)Av + aoff + (long)gm * lda + k0 + sc;
                    if (gm < M) { pa0[s] = *(const float4*)p; pa1[s] = *(const float4*)(p + 4); }
                    else { pa0[s] = {0,0,0,0}; pa1[s] = {0,0,0,0}; }
                } else {
                    pa[s] = (gm < M) ? *(const uint4*)((const bf16*)Av + aoff + (long)gm * lda + k0 + sc)
                                     : (uint4){0,0,0,0};
                }
                int gn = n0 + r;
                if (B_F32) {
                    const float* p = (const float*)Bv + boff + (long)gn * ldb + k0 + sc;
                    if (gn < N) { pb0[s] = *(const float4*)p; pb1[s] = *(const float4*)(p + 4); }
                    else { pb0[s] = {0,0,0,0}; pb1[s] = {0,0,0,0}; }
                } else {
                    pb[s] = (gn < N) ? *(const uint4*)((const bf16*)Bv + boff + (long)gn * ldb + k0 + sc)
                                     : (uint4){0,0,0,0};
                }
            }
        }

#pragma unroll
        for (int ks = 0; ks < 2; ks++) {
            short8 af[4], bfr[4];
#pragma unroll
            for (int i = 0; i < 4; i++)
                af[i] = *(const short8*)(&As[(wm + i * 16 + l16) * LDK + ks * 32 + quad * 8]);
#pragma unroll
            for (int j = 0; j < 4; j++)
                bfr[j] = *(const short8*)(&Bs[(wn + j * 16 + l16) * LDK + ks * 32 + quad * 8]);
#pragma unroll
            for (int i = 0; i < 4; i++)
#pragma unroll
                for (int j = 0; j < 4; j++)
                    acc[i][j] = __builtin_amdgcn_mfma_f32_16x16x32_bf16(af[i], bfr[j], acc[i][j], 0, 0, 0);
        }
    }

#pragma unroll
    for (int i = 0; i < 4; i++) {
        int row = m0 + wm + i * 16 + quad * 4;
#pragma unroll
        for (int j = 0; j < 4; j++) {
            int col = n0 + wn + j * 16 + l16;
            if (col >= N) continue;
#pragma unroll
            for (int v = 0; v < 4; v++) {
                int r = row + v;
                if (r < M) {
                    float val = acc[i][j][v];
                    if (OUT_BF16)
                        ((bf16*)Cv)[coff + (long)r * ldc + col] = __float2bfloat16(val);
                    else
                        ((float*)Cv)[coff + (long)r * ldc + col] = val;
                }
            }
        }
    }
}

// ---------------------------------------------------------------------------
// Fused QK^T + online softmax, ONE batch (round-4 PROVEN, unchanged).
// ---------------------------------------------------------------------------
__global__ void __launch_bounds__(256) attn_softmax(
    const bf16* __restrict__ Q, const bf16* __restrict__ Kb, bf16* __restrict__ Wts)
{
    __shared__ __align__(16) bf16 Ks[64 * 72];

    int h = blockIdx.y;
    const bf16* Qbh = Q  + (long)h * 262144;
    const bf16* Kbh = Kb + (long)h * 262144;
    bf16* W = Wts + (long)h * 1048576;

    int tid  = threadIdx.x;
    int lane = tid & 63;
    int wave = tid >> 6;
    int quad = lane >> 4;
    int l16  = lane & 15;
    int q0 = blockIdx.x * 64 + wave * 16;

    short8 a0 = *(const short8*)(Qbh + (long)(q0 + l16) * 64 + quad * 8);
    short8 a1 = *(const short8*)(Qbh + (long)(q0 + l16) * 64 + 32 + quad * 8);

    int sr = tid >> 3;
    int sc = (tid & 7) * 8;

    const float scale = 0.125f;
    float m_v[4] = {-1e30f, -1e30f, -1e30f, -1e30f};
    float l_v[4] = {0.f, 0.f, 0.f, 0.f};

    for (int t = 0; t < 16; t++) {
        __syncthreads();
        const bf16* src = Kbh + (long)(t * 64 + sr) * 64 + sc;
        *(uint4*)(&Ks[sr * 72 + sc])        = *(const uint4*)src;
        *(uint4*)(&Ks[(sr + 32) * 72 + sc]) = *(const uint4*)(src + 32 * 64);
        __syncthreads();
#pragma unroll
        for (int j = 0; j < 4; j++) {
            short8 b0 = *(const short8*)(&Ks[(j * 16 + l16) * 72 + quad * 8]);
            short8 b1 = *(const short8*)(&Ks[(j * 16 + l16) * 72 + 32 + quad * 8]);
            floatx4 acc = {0.f, 0.f, 0.f, 0.f};
            acc = __builtin_amdgcn_mfma_f32_16x16x32_bf16(a0, b0, acc, 0, 0, 0);
            acc = __builtin_amdgcn_mfma_f32_16x16x32_bf16(a1, b1, acc, 0, 0, 0);
#pragma unroll
            for (int v = 0; v < 4; v++) {
                float s  = acc[v] * scale;
                float nm = fmaxf(m_v[v], s);
                l_v[v] = l_v[v] * __expf(m_v[v] - nm) + __expf(s - nm);
                m_v[v] = nm;
            }
        }
    }

#pragma unroll
    for (int d = 1; d < 16; d <<= 1) {
#pragma unroll
        for (int v = 0; v < 4; v++) {
            float om = __shfl_xor(m_v[v], d);
            float ol = __shfl_xor(l_v[v], d);
            float nm = fmaxf(m_v[v], om);
            l_v[v] = l_v[v] * __expf(m_v[v] - nm) + ol * __expf(om - nm);
            m_v[v] = nm;
        }
    }
    float linv[4];
#pragma unroll
    for (int v = 0; v < 4; v++) linv[v] = 1.0f / l_v[v];

    for (int t = 0; t < 16; t++) {
        __syncthreads();
        const bf16* src = Kbh + (long)(t * 64 + sr) * 64 + sc;
        *(uint4*)(&Ks[sr * 72 + sc])        = *(const uint4*)src;
        *(uint4*)(&Ks[(sr + 32) * 72 + sc]) = *(const uint4*)(src + 32 * 64);
        __syncthreads();
#pragma unroll
        for (int j = 0; j < 4; j++) {
            short8 b0 = *(const short8*)(&Ks[(j * 16 + l16) * 72 + quad * 8]);
            short8 b1 = *(const short8*)(&Ks[(j * 16 + l16) * 72 + 32 + quad * 8]);
            floatx4 acc = {0.f, 0.f, 0.f, 0.f};
            acc = __builtin_amdgcn_mfma_f32_16x16x32_bf16(a0, b0, acc, 0, 0, 0);
            acc = __builtin_amdgcn_mfma_f32_16x16x32_bf16(a1, b1, acc, 0, 0, 0);
#pragma unroll
            for (int v = 0; v < 4; v++) {
                float w = __expf(acc[v] * scale - m_v[v]) * linv[v];
                W[(long)(q0 + quad * 4 + v) * 1024 + t * 64 + j * 16 + l16] = __float2bfloat16(w);
            }
        }
    }
}

// ---------------------------------------------------------------------------
__global__ void __launch_bounds__(256) cast_bf16_k(
    const float* __restrict__ in, bf16* __restrict__ out, int n4)
{
    int i = blockIdx.x * 256 + threadIdx.x;
    if (i >= n4) return;
    float4 v = ((const float4*)in)[i];
    bf16 t[4] = {__float2bfloat16(v.x), __float2bfloat16(v.y),
                 __float2bfloat16(v.z), __float2bfloat16(v.w)};
    ((uint2*)out)[i] = *(const uint2*)t;
}

__global__ void __launch_bounds__(256) transpose_cast(
    const float* __restrict__ in, bf16* __restrict__ out, int R, int C)
{
    __shared__ float t[32][33];
    int h = blockIdx.z;
    const float* inh = in + (long)h * R * C;
    bf16* outh = out + (long)h * R * C;
    int c0 = blockIdx.x * 32, r0 = blockIdx.y * 32;
    int tx = threadIdx.x, ty = threadIdx.y;
#pragma unroll
    for (int i = 0; i < 32; i += 8)
        t[ty + i][tx] = inh[(long)(r0 + ty + i) * C + c0 + tx];
    __syncthreads();
#pragma unroll
    for (int i = 0; i < 32; i += 8)
        outh[(long)(c0 + ty + i) * R + r0 + tx] = __float2bfloat16(t[tx][ty + i]);
}

// sum 16 fp32 partials of 1M elems each -> out (float4 per thread)
__global__ void __launch_bounds__(256) reduce16_k(
    const float* __restrict__ part, float* __restrict__ out)
{
    int i = blockIdx.x * 256 + threadIdx.x;
    float4 s = ((const float4*)part)[i];
#pragma unroll
    for (int c = 1; c < 16; c++) {
        float4 p = ((const float4*)part)[c * 262144 + i];
        s.x += p.x; s.y += p.y; s.z += p.z; s.w += p.w;
    }
    ((float4*)out)[i] = s;
}

// ---------------------------------------------------------------------------
// Workspace (MB, max 180 — proven):
//   wqt 0..2 | wkt 2..4 | wvt 4..36 | wob 36..68 | qb 68..76 | kb 76..84 |
//   vt_b 84..116 | wts_b 116..148 | att_b 148..180
//   out_part overlays 84..148 (vt_b/wts_b dead when final GEMM runs).
//   value_bf overlays 148..150 (att_b region; dead until PV GEMM, which runs
//   after vt GEMM has consumed value_bf — stream-ordered, safe).
// ---------------------------------------------------------------------------
extern "C" void kernel_launch(void* const* d_in, const int* in_sizes, int n_in,
                              void* d_out, int out_size, void* d_ws, size_t ws_size,
                              hipStream_t stream) {
    const float* query = (const float*)d_in[0];
    const float* key   = (const float*)d_in[1];
    const float* value = (const float*)d_in[2];
    const float* w_q   = (const float*)d_in[3];
    const float* w_k   = (const float*)d_in[4];
    const float* w_v   = (const float*)d_in[5];
    const float* w_o   = (const float*)d_in[6];
    float* out = (float*)d_out;

    char* ws = (char*)d_ws;
    const size_t MB = (size_t)1 << 20;
    bf16* wqt      = (bf16*)(ws + 0 * MB);
    bf16* wkt      = (bf16*)(ws + 2 * MB);
    bf16* wvt      = (bf16*)(ws + 4 * MB);
    bf16* wob      = (bf16*)(ws + 36 * MB);
    bf16* qb       = (bf16*)(ws + 68 * MB);
    bf16* kb       = (bf16*)(ws + 76 * MB);
    bf16* vt_b     = (bf16*)(ws + 84 * MB);
    bf16* wts_b    = (bf16*)(ws + 116 * MB);
    bf16* att_b    = (bf16*)(ws + 148 * MB);
    bf16* value_bf = (bf16*)(ws + 148 * MB);    // 2 MB overlay on att_b head
    float* out_part = (float*)(ws + 84 * MB);   // 64 MB overlay

    // weight prep
    transpose_cast<<<dim3(2, 32, 16),  dim3(32, 8), 0, stream>>>(w_q, wqt, 1024, 64);
    transpose_cast<<<dim3(2, 32, 16),  dim3(32, 8), 0, stream>>>(w_k, wkt, 1024, 64);
    transpose_cast<<<dim3(32, 32, 16), dim3(32, 8), 0, stream>>>(w_v, wvt, 1024, 1024);
    cast_bf16_k<<<16384, 256, 0, stream>>>(w_o, wob, 1024 * 16384 / 4);

    // Q/K projections (small, N=64 — old guarded reg-staged path)
    gemm_nt<true, true, false><<<dim3(1, 32, 16), 256, 0, stream>>>(
        query, wqt, qb, 4096, 64, 1024, 1024, 1024, 64, 0L, 65536L, 262144L);
    gemm_nt<true, true, false><<<dim3(1, 32, 16), 256, 0, stream>>>(
        key, wkt, kb, 4096, 64, 1024, 1024, 1024, 64, 0L, 65536L, 262144L);

    for (int b = 0; b < 4; b++) {
        // cast this batch's value to bf16 (enables global_load_lds path)
        cast_bf16_k<<<1024, 256, 0, stream>>>(value + (long)b * 1048576, value_bf, 262144);

        // V^T proj: vt_b[h][v][m] = wvt[h][v][d] . value_b[m][d]^T
        gemm_nt_256<true><<<dim3(4, 4, 16), 512, 0, stream>>>(
            wvt, value_bf, vt_b,
            1024, 1024, 1024, 1024, 1048576L, 0L, 1048576L);

        // QK^T + softmax -> wts_b[h][q][m]
        attn_softmax<<<dim3(16, 16), 256, 0, stream>>>(
            qb + (long)b * 65536, kb + (long)b * 65536, wts_b);

        // PV^T: att_b[v][h*1024+q] = vt_b[h][v][m] . wts_b[h][q][m]^T
        gemm_nt_256<true><<<dim3(4, 4, 16), 512, 0, stream>>>(
            vt_b, wts_b, att_b,
            1024, 1024, 1024, 16384, 1048576L, 1048576L, 1024L);

        // final split-K over heads: out_part[h][d][v] = wo[d][h*1024+q] . att_b[v][h*1024+q]^T
        gemm_nt_256<false><<<dim3(4, 4, 16), 512, 0, stream>>>(
            wob, att_b, out_part,
            1024, 16384, 16384, 1024, 1024L, 1024L, 1048576L);

        // reduce 16 partials -> out[b]
        reduce16_k<<<1024, 256, 0, stream>>>(out_part, out + (long)b * 1048576);
    }

    (void)in_sizes; (void)n_in; (void)out_size; (void)ws_size;
}

// Round 7
// 878.802 us; speedup vs baseline: 1.0488x; 1.0037x over previous
//
#include <hip/hip_runtime.h>
#include <hip/hip_bf16.h>

typedef __hip_bfloat16 bf16;
typedef __attribute__((ext_vector_type(8))) short short8;
typedef __attribute__((ext_vector_type(4))) float floatx4;

#define BK 64
#define LDK 72  // old reg-staged path only

// async global->LDS, 16B per lane, linear dest (wave-uniform base + lane*16)
__device__ __forceinline__ void gload_lds16(const void* g, void* l) {
    __builtin_amdgcn_global_load_lds(
        (const __attribute__((address_space(1))) void*)g,
        (__attribute__((address_space(3))) void*)l, 16, 0, 0);
}

// ---------------------------------------------------------------------------
// 256x256-tile NT GEMM — m201-style 4-phase/K-tile schedule. Identical sync
// structure to the round-5-verified kernel (same ring, same barriers, same
// vmcnt placement -> same race ledger), but UNPINNED:
//   * zero sched_barrier(0)  (no inline-asm ds_reads -> rule 18 not needed;
//     m141: order-pinning cost 40% on the m97 kernel)
//   * __builtin_amdgcn_s_barrier() instead of asm-with-memory-clobber
//   * stage source/dest bases hoisted out of the K-loop (1 add per stage)
// Ring (regions named by read phase):
//   AX = A rows {0-63,128-191}    read P0 (af_lo)
//   BX = B rows {0-31,64-95,128-159,192-223}   read P0 (bf01)
//   BY = B rows {32-63,96-127,160-191,224-255} read P1 (bf23)
//   AY = A rows {64-127,192-255}  read P2 (af_hi)
// K-tile kt, buf d = kt&1; phase = {reads; stage 1 unit; BAR; lgkm0;
//   setprio1; 16 MFMA; setprio0; BAR}:
//   P0: af_lo+bf01 ; stage AY(kt+1)->d^1 ; MFMA q00
//   P1: bf23       ; stage AX(kt+2)->d   ; MFMA q01
//   P2: af_hi      ; stage BX(kt+2)->d   ; MFMA q11
//   P3:            ; stage BY(kt+2)->d   ; vmcnt(6|0) ; MFMA q10
// Ledger (unchanged from r5, verified): each region's last reader is >=1
// barrier before its overwrite; vmcnt(6) = 3 units in flight -> all of tile
// kt+1 landed entering its phases; vmcnt(0) entering the last K-tile.
// Requires M=N=1024 per z-slice, K mult of 64, K>=128, bf16 A/B, grid (4,4,Z).
// ---------------------------------------------------------------------------
template<bool OUT_BF16>
__global__ void __launch_bounds__(512) gemm_nt_256(
    const bf16* __restrict__ A, const bf16* __restrict__ B, void* __restrict__ Cv,
    int K, int lda, int ldb, int ldc,
    long sA, long sB, long sC)
{
    __shared__ __align__(16) bf16 As[2][256 * 64];
    __shared__ __align__(16) bf16 Bs[2][256 * 64];

    int bx = blockIdx.x, by = blockIdx.y, bz = blockIdx.z;
    // XCD swizzle: each XCD owns contiguous z-slices (bijective, Z%8==0)
    if (gridDim.x == 4 && gridDim.y == 4 && (gridDim.z & 7) == 0) {
        int hw  = bx + (by << 2) + (bz << 4);
        int xcd = hw & 7;
        int idx = hw >> 3;
        int per = (int)(gridDim.z >> 3) << 4;   // blocks per XCD
        int nh  = xcd * per + idx;
        bx = nh & 3; by = (nh >> 2) & 3; bz = nh >> 4;
    }

    long aoff = (long)bz * sA + (long)by * 256 * lda;
    long boff = (long)bz * sB + (long)bx * 256 * ldb;
    long coff = (long)bz * sC;

    int tid  = threadIdx.x;
    int lane = tid & 63;
    int wave = tid >> 6;           // 0..7
    int quad = lane >> 4;
    int l16  = lane & 15;
    int swz  = l16 & 7;            // row&7 at fragment-read time
    int wm = (wave >> 2) * 128;    // 2 M-waves
    int wn = (wave & 3) * 64;      // 4 N-waves

    // staging geometry: one gload_lds per thread covers a 64-row unit
    // (512 threads x 16B = 8KB). Dest linear wave-uniform base + lane*16;
    // source carries the inverse XOR swizzle.
    int srow   = tid >> 3;                    // 0..63
    int schunk = (tid & 7) ^ (srow & 7);      // swizzled source chunk

    const bf16* Asrc = A + aoff;
    const bf16* Bsrc = B + boff;

    // ---- hoisted per-thread stage source bases (constant across K-loop) ----
    const bf16* aS0 = Asrc + (long)(  0 + srow) * lda + schunk * 8;  // AX lo
    const bf16* aS1 = Asrc + (long)(128 + srow) * lda + schunk * 8;  // AX hi
    const bf16* aS2 = Asrc + (long)( 64 + srow) * lda + schunk * 8;  // AY lo
    const bf16* aS3 = Asrc + (long)(192 + srow) * lda + schunk * 8;  // AY hi
    int rBX0 = (srow < 32) ? (  0 + srow) : ( 64 + srow - 32);
    int rBX1 = (srow < 32) ? (128 + srow) : (192 + srow - 32);
    int rBY0 = (srow < 32) ? ( 32 + srow) : ( 96 + srow - 32);
    int rBY1 = (srow < 32) ? (160 + srow) : (224 + srow - 32);
    const bf16* bS0 = Bsrc + (long)rBX0 * ldb + schunk * 8;
    const bf16* bS1 = Bsrc + (long)rBX1 * ldb + schunk * 8;
    const bf16* bS2 = Bsrc + (long)rBY0 * ldb + schunk * 8;
    const bf16* bS3 = Bsrc + (long)rBY1 * ldb + schunk * 8;
    // hoisted LDS dest offsets (elements)
    int dA0 = (  0 + (wave << 3)) * 64;
    int dA1 = (128 + (wave << 3)) * 64;
    int dA2 = ( 64 + (wave << 3)) * 64;
    int dA3 = (192 + (wave << 3)) * 64;
    int dBX0 = ((wave < 4) ? (  0 + (wave << 3)) : ( 64 + ((wave - 4) << 3))) * 64;
    int dBX1 = ((wave < 4) ? (128 + (wave << 3)) : (192 + ((wave - 4) << 3))) * 64;
    int dBY0 = ((wave < 4) ? ( 32 + (wave << 3)) : ( 96 + ((wave - 4) << 3))) * 64;
    int dBY1 = ((wave < 4) ? (160 + (wave << 3)) : (224 + ((wave - 4) << 3))) * 64;

    auto STAGE_AX = [&](int db_, int kt) {
        long ko = (long)kt * BK;
        gload_lds16(aS0 + ko, &As[db_][dA0]);
        gload_lds16(aS1 + ko, &As[db_][dA1]);
    };
    auto STAGE_AY = [&](int db_, int kt) {
        long ko = (long)kt * BK;
        gload_lds16(aS2 + ko, &As[db_][dA2]);
        gload_lds16(aS3 + ko, &As[db_][dA3]);
    };
    auto STAGE_BX = [&](int db_, int kt) {
        long ko = (long)kt * BK;
        gload_lds16(bS0 + ko, &Bs[db_][dBX0]);
        gload_lds16(bS1 + ko, &Bs[db_][dBX1]);
    };
    auto STAGE_BY = [&](int db_, int kt) {
        long ko = (long)kt * BK;
        gload_lds16(bS2 + ko, &Bs[db_][dBY0]);
        gload_lds16(bS3 + ko, &Bs[db_][dBY1]);
    };

    floatx4 acc[8][4] = {};
    const int nt = K / BK;   // REQUIRES nt >= 2

    // ---- prologue: 7 units in ring order (tile0 all 4 + tile1 AX,BX,BY);
    // vmcnt(6) -> tile0 fully landed, tile1's 3 units (6 loads) in flight.
    STAGE_AX(0, 0); STAGE_BX(0, 0); STAGE_BY(0, 0); STAGE_AY(0, 0);
    STAGE_AX(1, 1); STAGE_BX(1, 1); STAGE_BY(1, 1);
    asm volatile("s_waitcnt vmcnt(6)" ::: "memory");
    __builtin_amdgcn_s_barrier();

    short8 af[4][2], bf[4][2];
    int db = 0;
    for (int kt = 0; kt < nt; kt++) {
        const bf16* as = As[db];
        const bf16* bs = Bs[db];
        bool st1 = (kt + 1 < nt);
        bool st2 = (kt + 2 < nt);

        // ===== P0: read af_lo + bf01 ; stage AY(kt+1)->d^1 ; MFMA q00
#pragma unroll
        for (int i = 0; i < 4; i++)
#pragma unroll
            for (int ks = 0; ks < 2; ks++)
                af[i][ks] = *(const short8*)(&as[(wm + i * 16 + l16) * 64 + (((ks << 2) | quad) ^ swz) * 8]);
#pragma unroll
        for (int j = 0; j < 2; j++)
#pragma unroll
            for (int ks = 0; ks < 2; ks++)
                bf[j][ks] = *(const short8*)(&bs[(wn + j * 16 + l16) * 64 + (((ks << 2) | quad) ^ swz) * 8]);
        if (st1) STAGE_AY(db ^ 1, kt + 1);
        __builtin_amdgcn_s_barrier();
        asm volatile("s_waitcnt lgkmcnt(0)" ::: "memory");
        __builtin_amdgcn_s_setprio(1);
#pragma unroll
        for (int i = 0; i < 4; i++)
#pragma unroll
            for (int j = 0; j < 2; j++)
#pragma unroll
                for (int ks = 0; ks < 2; ks++)
                    acc[i][j] = __builtin_amdgcn_mfma_f32_16x16x32_bf16(af[i][ks], bf[j][ks], acc[i][j], 0, 0, 0);
        __builtin_amdgcn_s_setprio(0);
        __builtin_amdgcn_s_barrier();

        // ===== P1: read bf23 ; stage AX(kt+2)->d ; MFMA q01
#pragma unroll
        for (int j = 2; j < 4; j++)
#pragma unroll
            for (int ks = 0; ks < 2; ks++)
                bf[j][ks] = *(const short8*)(&bs[(wn + j * 16 + l16) * 64 + (((ks << 2) | quad) ^ swz) * 8]);
        if (st2) STAGE_AX(db, kt + 2);
        __builtin_amdgcn_s_barrier();
        asm volatile("s_waitcnt lgkmcnt(0)" ::: "memory");
        __builtin_amdgcn_s_setprio(1);
#pragma unroll
        for (int i = 0; i < 4; i++)
#pragma unroll
            for (int j = 2; j < 4; j++)
#pragma unroll
                for (int ks = 0; ks < 2; ks++)
                    acc[i][j] = __builtin_amdgcn_mfma_f32_16x16x32_bf16(af[i][ks], bf[j][ks], acc[i][j], 0, 0, 0);
        __builtin_amdgcn_s_setprio(0);
        __builtin_amdgcn_s_barrier();

        // ===== P2: read af_hi ; stage BX(kt+2)->d ; MFMA q11
#pragma unroll
        for (int i = 0; i < 4; i++)
#pragma unroll
            for (int ks = 0; ks < 2; ks++)
                af[i][ks] = *(const short8*)(&as[(wm + 64 + i * 16 + l16) * 64 + (((ks << 2) | quad) ^ swz) * 8]);
        if (st2) STAGE_BX(db, kt + 2);
        __builtin_amdgcn_s_barrier();
        asm volatile("s_waitcnt lgkmcnt(0)" ::: "memory");
        __builtin_amdgcn_s_setprio(1);
#pragma unroll
        for (int i = 0; i < 4; i++)
#pragma unroll
            for (int j = 2; j < 4; j++)
#pragma unroll
                for (int ks = 0; ks < 2; ks++)
                    acc[i + 4][j] = __builtin_amdgcn_mfma_f32_16x16x32_bf16(af[i][ks], bf[j][ks], acc[i + 4][j], 0, 0, 0);
        __builtin_amdgcn_s_setprio(0);
        __builtin_amdgcn_s_barrier();

        // ===== P3: stage BY(kt+2)->d ; vmcnt(6|0) ; MFMA q10
        if (st2) STAGE_BY(db, kt + 2);
        if (st2) asm volatile("s_waitcnt vmcnt(6)" ::: "memory");
        else     asm volatile("s_waitcnt vmcnt(0)" ::: "memory");
        __builtin_amdgcn_s_barrier();
        __builtin_amdgcn_s_setprio(1);
#pragma unroll
        for (int i = 0; i < 4; i++)
#pragma unroll
            for (int j = 0; j < 2; j++)
#pragma unroll
                for (int ks = 0; ks < 2; ks++)
                    acc[i + 4][j] = __builtin_amdgcn_mfma_f32_16x16x32_bf16(af[i][ks], bf[j][ks], acc[i + 4][j], 0, 0, 0);
        __builtin_amdgcn_s_setprio(0);
        __builtin_amdgcn_s_barrier();

        db ^= 1;
    }

    // epilogue: C/D layout row = quad*4+reg, col = lane&15
#pragma unroll
    for (int i = 0; i < 8; i++) {
        int row = by * 256 + wm + i * 16 + quad * 4;
#pragma unroll
        for (int j = 0; j < 4; j++) {
            int col = bx * 256 + wn + j * 16 + l16;
#pragma unroll
            for (int v = 0; v < 4; v++) {
                float val = acc[i][j][v];
                if (OUT_BF16)
                    ((bf16*)Cv)[coff + (long)(row + v) * ldc + col] = __float2bfloat16(val);
                else
                    ((float*)Cv)[coff + (long)(row + v) * ldc + col] = val;
            }
        }
    }
}

// ---------------------------------------------------------------------------
// OLD reg-staged NT GEMM: kept only for the small Q/K projections
// (N=64 needs bounds guards; A is f32 converted at LDS-store time).
// ---------------------------------------------------------------------------
template<bool OUT_BF16, bool A_F32, bool B_F32>
__global__ void __launch_bounds__(256) gemm_nt(
    const void* __restrict__ Av, const void* __restrict__ Bv, void* __restrict__ Cv,
    int M, int N, int K, int lda, int ldb, int ldc,
    long sA, long sB, long sC)
{
    __shared__ __align__(16) bf16 As[128 * LDK];
    __shared__ __align__(16) bf16 Bs[128 * LDK];

    int bx = blockIdx.x, by = blockIdx.y, bz = blockIdx.z;

    long aoff = (long)bz * sA;
    long boff = (long)bz * sB;
    long coff = (long)bz * sC;

    int m0 = by * 128;
    int n0 = bx * 128;
    int tid  = threadIdx.x;
    int lane = tid & 63;
    int wave = tid >> 6;
    int quad = lane >> 4;
    int l16  = lane & 15;
    int wm = (wave >> 1) * 64;
    int wn = (wave & 1) * 64;

    int sr = tid >> 3;
    int sc = (tid & 7) * 8;

    floatx4 acc[4][4] = {};

    uint4  pa[4], pb[4];
    float4 pa0[4], pa1[4], pb0[4], pb1[4];

    const int nt = K / BK;

#pragma unroll
    for (int s = 0; s < 4; s++) {
        int r = sr + 32 * s;
        int gm = m0 + r;
        if (A_F32) {
            const float* p = (const float*)Av + aoff + (long)gm * lda + sc;
            if (gm < M) { pa0[s] = *(const float4*)p; pa1[s] = *(const float4*)(p + 4); }
            else { pa0[s] = {0,0,0,0}; pa1[s] = {0,0,0,0}; }
        } else {
            pa[s] = (gm < M) ? *(const uint4*)((const bf16*)Av + aoff + (long)gm * lda + sc)
                             : (uint4){0,0,0,0};
        }
        int gn = n0 + r;
        if (B_F32) {
            const float* p = (const float*)Bv + boff + (long)gn * ldb + sc;
            if (gn < N) { pb0[s] = *(const float4*)p; pb1[s] = *(const float4*)(p + 4); }
            else { pb0[s] = {0,0,0,0}; pb1[s] = {0,0,0,0}; }
        } else {
            pb[s] = (gn < N) ? *(const uint4*)((const bf16*)Bv + boff + (long)gn * ldb + sc)
                             : (uint4){0,0,0,0};
        }
    }

    for (int kt = 0; kt < nt; kt++) {
        __syncthreads();
#pragma unroll
        for (int s = 0; s < 4; s++) {
            int r = sr + 32 * s;
            if (A_F32) {
                bf16 t[8];
                t[0]=__float2bfloat16(pa0[s].x); t[1]=__float2bfloat16(pa0[s].y);
                t[2]=__float2bfloat16(pa0[s].z); t[3]=__float2bfloat16(pa0[s].w);
                t[4]=__float2bfloat16(pa1[s].x); t[5]=__float2bfloat16(pa1[s].y);
                t[6]=__float2bfloat16(pa1[s].z); t[7]=__float2bfloat16(pa1[s].w);
                *(uint4*)(&As[r * LDK + sc]) = *(const uint4*)t;
            } else {
                *(uint4*)(&As[r * LDK + sc]) = pa[s];
            }
            if (B_F32) {
                bf16 t[8];
                t[0]=__float2bfloat16(pb0[s].x); t[1]=__float2bfloat16(pb0[s].y);
                t[2]=__float2bfloat16(pb0[s].z); t[3]=__float2bfloat16(pb0[s].w);
                t[4]=__float2bfloat16(pb1[s].x); t[5]=__float2bfloat16(pb1[s].y);
                t[6]=__float2bfloat16(pb1[s].z); t[7]=__float2bfloat16(pb1[s].w);
                *(uint4*)(&Bs[r * LDK + sc]) = *(const uint4*)t;
            } else {
                *(uint4*)(&Bs[r * LDK + sc]) = pb[s];
            }
        }
        __syncthreads();

        if (kt + 1 < nt) {
            int k0 = (kt + 1) * BK;
#pragma unroll
            for (int s = 0; s < 4; s++) {
                int r = sr + 32 * s;
                int gm = m0 + r;
                if (A_F32) {
                    const float* p = (const float*)Av + aoff + (long)gm * lda + k0 + sc;
                    if (gm < M) { pa0[s] = *(const float4*)p; pa1[s] = *(const float4*)(p + 4); }
                    else { pa0[s] = {0,0,0,0}; pa1[s] = {0,0,0,0}; }
                } else {
                    pa[s] = (gm < M) ? *(const uint4*)((const bf16*)Av + aoff + (long)gm * lda + k0 + sc)
                                     : (uint4){0,0,0,0};
                }
                int gn = n0 + r;
                if (B_F32) {
                    const float* p = (const float*)Bv + boff + (long)gn * ldb + k0 + sc;
                    if (gn < N) { pb0[s] = *(const float4*)p; pb1[s] = *(const float4*)(p + 4); }
                    else { pb0[s] = {0,0,0,0}; pb1[s] = {0,0,0,0}; }
                } else {
                    pb[s] = (gn < N) ? *(const uint4*)((const bf16*)Bv + boff + (long)gn * ldb + k0 + sc)
                                     : (uint4){0,0,0,0};
                }
            }
        }

#pragma unroll
        for (int ks = 0; ks < 2; ks++) {
            short8 af[4], bfr[4];
#pragma unroll
            for (int i = 0; i < 4; i++)
                af[i] = *(const short8*)(&As[(wm + i * 16 + l16) * LDK + ks * 32 + quad * 8]);
#pragma unroll
            for (int j = 0; j < 4; j++)
                bfr[j] = *(const short8*)(&Bs[(wn + j * 16 + l16) * LDK + ks * 32 + quad * 8]);
#pragma unroll
            for (int i = 0; i < 4; i++)
#pragma unroll
                for (int j = 0; j < 4; j++)
                    acc[i][j] = __builtin_amdgcn_mfma_f32_16x16x32_bf16(af[i], bfr[j], acc[i][j], 0, 0, 0);
        }
    }

#pragma unroll
    for (int i = 0; i < 4; i++) {
        int row = m0 + wm + i * 16 + quad * 4;
#pragma unroll
        for (int j = 0; j < 4; j++) {
            int col = n0 + wn + j * 16 + l16;
            if (col >= N) continue;
#pragma unroll
            for (int v = 0; v < 4; v++) {
                int r = row + v;
                if (r < M) {
                    float val = acc[i][j][v];
                    if (OUT_BF16)
                        ((bf16*)Cv)[coff + (long)r * ldc + col] = __float2bfloat16(val);
                    else
                        ((float*)Cv)[coff + (long)r * ldc + col] = val;
                }
            }
        }
    }
}

// ---------------------------------------------------------------------------
// Fused QK^T + online softmax, ONE batch (round-4 PROVEN, unchanged).
// ---------------------------------------------------------------------------
__global__ void __launch_bounds__(256) attn_softmax(
    const bf16* __restrict__ Q, const bf16* __restrict__ Kb, bf16* __restrict__ Wts)
{
    __shared__ __align__(16) bf16 Ks[64 * 72];

    int h = blockIdx.y;
    const bf16* Qbh = Q  + (long)h * 262144;
    const bf16* Kbh = Kb + (long)h * 262144;
    bf16* W = Wts + (long)h * 1048576;

    int tid  = threadIdx.x;
    int lane = tid & 63;
    int wave = tid >> 6;
    int quad = lane >> 4;
    int l16  = lane & 15;
    int q0 = blockIdx.x * 64 + wave * 16;

    short8 a0 = *(const short8*)(Qbh + (long)(q0 + l16) * 64 + quad * 8);
    short8 a1 = *(const short8*)(Qbh + (long)(q0 + l16) * 64 + 32 + quad * 8);

    int sr = tid >> 3;
    int sc = (tid & 7) * 8;

    const float scale = 0.125f;
    float m_v[4] = {-1e30f, -1e30f, -1e30f, -1e30f};
    float l_v[4] = {0.f, 0.f, 0.f, 0.f};

    for (int t = 0; t < 16; t++) {
        __syncthreads();
        const bf16* src = Kbh + (long)(t * 64 + sr) * 64 + sc;
        *(uint4*)(&Ks[sr * 72 + sc])        = *(const uint4*)src;
        *(uint4*)(&Ks[(sr + 32) * 72 + sc]) = *(const uint4*)(src + 32 * 64);
        __syncthreads();
#pragma unroll
        for (int j = 0; j < 4; j++) {
            short8 b0 = *(const short8*)(&Ks[(j * 16 + l16) * 72 + quad * 8]);
            short8 b1 = *(const short8*)(&Ks[(j * 16 + l16) * 72 + 32 + quad * 8]);
            floatx4 acc = {0.f, 0.f, 0.f, 0.f};
            acc = __builtin_amdgcn_mfma_f32_16x16x32_bf16(a0, b0, acc, 0, 0, 0);
            acc = __builtin_amdgcn_mfma_f32_16x16x32_bf16(a1, b1, acc, 0, 0, 0);
#pragma unroll
            for (int v = 0; v < 4; v++) {
                float s  = acc[v] * scale;
                float nm = fmaxf(m_v[v], s);
                l_v[v] = l_v[v] * __expf(m_v[v] - nm) + __expf(s - nm);
                m_v[v] = nm;
            }
        }
    }

#pragma unroll
    for (int d = 1; d < 16; d <<= 1) {
#pragma unroll
        for (int v = 0; v < 4; v++) {
            float om = __shfl_xor(m_v[v], d);
            float ol = __shfl_xor(l_v[v], d);
            float nm = fmaxf(m_v[v], om);
            l_v[v] = l_v[v] * __expf(m_v[v] - nm) + ol * __expf(om - nm);
            m_v[v] = nm;
        }
    }
    float linv[4];
#pragma unroll
    for (int v = 0; v < 4; v++) linv[v] = 1.0f / l_v[v];

    for (int t = 0; t < 16; t++) {
        __syncthreads();
        const bf16* src = Kbh + (long)(t * 64 + sr) * 64 + sc;
        *(uint4*)(&Ks[sr * 72 + sc])        = *(const uint4*)src;
        *(uint4*)(&Ks[(sr + 32) * 72 + sc]) = *(const uint4*)(src + 32 * 64);
        __syncthreads();
#pragma unroll
        for (int j = 0; j < 4; j++) {
            short8 b0 = *(const short8*)(&Ks[(j * 16 + l16) * 72 + quad * 8]);
            short8 b1 = *(const short8*)(&Ks[(j * 16 + l16) * 72 + 32 + quad * 8]);
            floatx4 acc = {0.f, 0.f, 0.f, 0.f};
            acc = __builtin_amdgcn_mfma_f32_16x16x32_bf16(a0, b0, acc, 0, 0, 0);
            acc = __builtin_amdgcn_mfma_f32_16x16x32_bf16(a1, b1, acc, 0, 0, 0);
#pragma unroll
            for (int v = 0; v < 4; v++) {
                float w = __expf(acc[v] * scale - m_v[v]) * linv[v];
                W[(long)(q0 + quad * 4 + v) * 1024 + t * 64 + j * 16 + l16] = __float2bfloat16(w);
            }
        }
    }
}

// ---------------------------------------------------------------------------
__global__ void __launch_bounds__(256) cast_bf16_k(
    const float* __restrict__ in, bf16* __restrict__ out, int n4)
{
    int i = blockIdx.x * 256 + threadIdx.x;
    if (i >= n4) return;
    float4 v = ((const float4*)in)[i];
    bf16 t[4] = {__float2bfloat16(v.x), __float2bfloat16(v.y),
                 __float2bfloat16(v.z), __float2bfloat16(v.w)};
    ((uint2*)out)[i] = *(const uint2*)t;
}

__global__ void __launch_bounds__(256) transpose_cast(
    const float* __restrict__ in, bf16* __restrict__ out, int R, int C)
{
    __shared__ float t[32][33];
    int h = blockIdx.z;
    const float* inh = in + (long)h * R * C;
    bf16* outh = out + (long)h * R * C;
    int c0 = blockIdx.x * 32, r0 = blockIdx.y * 32;
    int tx = threadIdx.x, ty = threadIdx.y;
#pragma unroll
    for (int i = 0; i < 32; i += 8)
        t[ty + i][tx] = inh[(long)(r0 + ty + i) * C + c0 + tx];
    __syncthreads();
#pragma unroll
    for (int i = 0; i < 32; i += 8)
        outh[(long)(c0 + ty + i) * R + r0 + tx] = __float2bfloat16(t[tx][ty + i]);
}

// sum 16 fp32 partials of 1M elems each -> out (float4 per thread)
__global__ void __launch_bounds__(256) reduce16_k(
    const float* __restrict__ part, float* __restrict__ out)
{
    int i = blockIdx.x * 256 + threadIdx.x;
    float4 s = ((const float4*)part)[i];
#pragma unroll
    for (int c = 1; c < 16; c++) {
        float4 p = ((const float4*)part)[c * 262144 + i];
        s.x += p.x; s.y += p.y; s.z += p.z; s.w += p.w;
    }
    ((float4*)out)[i] = s;
}

// ---------------------------------------------------------------------------
// Workspace (MB, max 180 — proven):
//   wqt 0..2 | wkt 2..4 | wvt 4..36 | wob 36..68 | qb 68..76 | kb 76..84 |
//   vt_b 84..116 | wts_b 116..148 | att_b 148..180
//   out_part overlays 84..148 (vt_b/wts_b dead when final GEMM runs).
//   value_bf overlays 148..150 (att_b region; dead until PV GEMM, which runs
//   after vt GEMM has consumed value_bf — stream-ordered, safe).
// ---------------------------------------------------------------------------
extern "C" void kernel_launch(void* const* d_in, const int* in_sizes, int n_in,
                              void* d_out, int out_size, void* d_ws, size_t ws_size,
                              hipStream_t stream) {
    const float* query = (const float*)d_in[0];
    const float* key   = (const float*)d_in[1];
    const float* value = (const float*)d_in[2];
    const float* w_q   = (const float*)d_in[3];
    const float* w_k   = (const float*)d_in[4];
    const float* w_v   = (const float*)d_in[5];
    const float* w_o   = (const float*)d_in[6];
    float* out = (float*)d_out;

    char* ws = (char*)d_ws;
    const size_t MB = (size_t)1 << 20;
    bf16* wqt      = (bf16*)(ws + 0 * MB);
    bf16* wkt      = (bf16*)(ws + 2 * MB);
    bf16* wvt      = (bf16*)(ws + 4 * MB);
    bf16* wob      = (bf16*)(ws + 36 * MB);
    bf16* qb       = (bf16*)(ws + 68 * MB);
    bf16* kb       = (bf16*)(ws + 76 * MB);
    bf16* vt_b     = (bf16*)(ws + 84 * MB);
    bf16* wts_b    = (bf16*)(ws + 116 * MB);
    bf16* att_b    = (bf16*)(ws + 148 * MB);
    bf16* value_bf = (bf16*)(ws + 148 * MB);    // 2 MB overlay on att_b head
    float* out_part = (float*)(ws + 84 * MB);   // 64 MB overlay

    // weight prep
    transpose_cast<<<dim3(2, 32, 16),  dim3(32, 8), 0, stream>>>(w_q, wqt, 1024, 64);
    transpose_cast<<<dim3(2, 32, 16),  dim3(32, 8), 0, stream>>>(w_k, wkt, 1024, 64);
    transpose_cast<<<dim3(32, 32, 16), dim3(32, 8), 0, stream>>>(w_v, wvt, 1024, 1024);
    cast_bf16_k<<<16384, 256, 0, stream>>>(w_o, wob, 1024 * 16384 / 4);

    // Q/K projections (small, N=64 — old guarded reg-staged path)
    gemm_nt<true, true, false><<<dim3(1, 32, 16), 256, 0, stream>>>(
        query, wqt, qb, 4096, 64, 1024, 1024, 1024, 64, 0L, 65536L, 262144L);
    gemm_nt<true, true, false><<<dim3(1, 32, 16), 256, 0, stream>>>(
        key, wkt, kb, 4096, 64, 1024, 1024, 1024, 64, 0L, 65536L, 262144L);

    for (int b = 0; b < 4; b++) {
        // cast this batch's value to bf16 (enables global_load_lds path)
        cast_bf16_k<<<1024, 256, 0, stream>>>(value + (long)b * 1048576, value_bf, 262144);

        // V^T proj: vt_b[h][v][m] = wvt[h][v][d] . value_b[m][d]^T
        gemm_nt_256<true><<<dim3(4, 4, 16), 512, 0, stream>>>(
            wvt, value_bf, vt_b,
            1024, 1024, 1024, 1024, 1048576L, 0L, 1048576L);

        // QK^T + softmax -> wts_b[h][q][m]
        attn_softmax<<<dim3(16, 16), 256, 0, stream>>>(
            qb + (long)b * 65536, kb + (long)b * 65536, wts_b);

        // PV^T: att_b[v][h*1024+q] = vt_b[h][v][m] . wts_b[h][q][m]^T
        gemm_nt_256<true><<<dim3(4, 4, 16), 512, 0, stream>>>(
            vt_b, wts_b, att_b,
            1024, 1024, 1024, 16384, 1048576L, 1048576L, 1024L);

        // final split-K over heads: out_part[h][d][v] = wo[d][h*1024+q] . att_b[v][h*1024+q]^T
        gemm_nt_256<false><<<dim3(4, 4, 16), 512, 0, stream>>>(
            wob, att_b, out_part,
            1024, 16384, 16384, 1024, 1024L, 1024L, 1048576L);

        // reduce 16 partials -> out[b]
        reduce16_k<<<1024, 256, 0, stream>>>(out_part, out + (long)b * 1048576);
    }

    (void)in_sizes; (void)n_in; (void)out_size; (void)ws_size;
}